// Round 1
// baseline (323.866 us; speedup 1.0000x reference)
//
#include <hip/hip_runtime.h>
#include <stdint.h>

#define BATCH 16
#define CH    128
#define HIN   128
#define WIN   128
#define PH    64
#define PW    64

// d_ws layout (bytes):
//   pooled : float [16][128][64][64]            = 33,554,432
//   abits  : u32   [2][16][64][64][4 words]     =  2,097,152   (uint4 per position)
//   wbits  : u32   [2][128][9 taps][4 words]    =     36,864   (uint4 per (o,tap))
//   wscale : float [2][128]                     =      1,024
#define OFF_ABITS  33554432u
#define OFF_WBITS  35651584u
#define OFF_WSCALE 35688448u

__global__ __launch_bounds__(256) void pool_pack(
    const float* __restrict__ x,
    const float* __restrict__ mvk1, const float* __restrict__ mvb1,
    const float* __restrict__ mvk2, const float* __restrict__ mvb2,
    float* __restrict__ pooled, uint32_t* __restrict__ abits)
{
    __shared__ float sp[CH][PW + 1];   // 128 x 65 floats = 33,280 B
    const int b  = blockIdx.y;
    const int ph = blockIdx.x;
    const int t  = threadIdx.x;
    const int pw = t & 63;
    const int c0 = t >> 6;             // 0..3

    // ---- pool 2x2 (coalesced float2 loads), write pooled + stage in LDS ----
    for (int cg = 0; cg < CH; cg += 4) {
        const int c = cg + c0;
        const float* xrow = x + (((size_t)(b * CH + c) * HIN) + 2 * ph) * WIN;
        const float2 r0 = *(const float2*)(xrow + 2 * pw);
        const float2 r1 = *(const float2*)(xrow + WIN + 2 * pw);
        const float pv = (r0.x + r0.y + r1.x + r1.y) * 0.25f;
        pooled[(size_t)(b * CH + c) * (PH * PW) + ph * PW + pw] = pv;
        sp[c][pw] = pv;
    }
    __syncthreads();

    // ---- pack sign bits: sel = t>>6 -> (branch, word-pair) ----
    const int branch = c0 >> 1;
    const int wp0    = (c0 & 1) * 2;
    const float* mvk = branch ? mvk2 : mvk1;
    const float* mvb = branch ? mvb2 : mvb1;
    for (int wi = 0; wi < 2; ++wi) {
        const int word = wp0 + wi;
        uint32_t bits = 0;
        #pragma unroll
        for (int j = 0; j < 32; ++j) {
            const int c = word * 32 + j;
            const float v = sp[c][pw] * mvk[c] + mvb[c];
            bits |= (v < 0.0f ? 1u : 0u) << j;
        }
        abits[((size_t)(branch * BATCH + b) * (PH * PW) + ph * PW + pw) * 4 + word] = bits;
    }
}

__global__ __launch_bounds__(64) void wprep(
    const float* __restrict__ W1, const float* __restrict__ W2,
    uint32_t* __restrict__ wbits, float* __restrict__ wscale)
{
    const int bo = blockIdx.x;         // branch*128 + o
    const int branch = bo >> 7;
    const int o = bo & 127;
    const float* Wt = (branch ? W2 : W1) + (size_t)o * (CH * 9);
    const int t = threadIdx.x;

    float s = 0.f;
    for (int i = t; i < CH * 9; i += 64) s += fabsf(Wt[i]);
    #pragma unroll
    for (int off = 32; off >= 1; off >>= 1) s += __shfl_down(s, off);
    if (t == 0) wscale[bo] = s * (1.0f / (CH * 9));

    if (t < 36) {
        const int tap  = t >> 2;       // 0..8  (kh*3+kw)
        const int word = t & 3;        // 0..3
        uint32_t bits = 0;
        for (int j = 0; j < 32; ++j) {
            const int c = word * 32 + j;
            const float wv = Wt[c * 9 + tap];
            bits |= (wv < 0.0f ? 1u : 0u) << j;
        }
        wbits[(bo * 9 + tap) * 4 + word] = bits;
    }
}

__device__ __forceinline__ int popc4(uint4 a, uint4 w) {
    return __popc(a.x ^ w.x) + __popc(a.y ^ w.y) + __popc(a.z ^ w.z) + __popc(a.w ^ w.w);
}

__global__ __launch_bounds__(256) void bconv_main(
    const uint32_t* __restrict__ abits_, const uint32_t* __restrict__ wbits_,
    const float* __restrict__ wscale, const float* __restrict__ pooled,
    const float* __restrict__ pb0_1, const float* __restrict__ alpha1, const float* __restrict__ pb1_1,
    const float* __restrict__ pb0_2, const float* __restrict__ alpha2, const float* __restrict__ pb1_2,
    float* __restrict__ out)
{
    __shared__ uint4 ha[10][66];       // halo of activation bit-words, 10,560 B
    const int bid    = blockIdx.x;     // ((branch*16 + b)*8 + ty)*2 + oh
    const int oh     = bid & 1;
    const int ty     = (bid >> 1) & 7;
    const int b      = (bid >> 4) & 15;
    const int branch = bid >> 8;
    const int t  = threadIdx.x;
    const int lc = t & 63;             // output col
    const int lr2 = t >> 6;            // 0..3 -> output rows ty*8+lr2*2 .. +1

    // ---- load activation halo bits into LDS ----
    const uint4* ab = (const uint4*)abits_ + (size_t)(branch * BATCH + b) * (PH * PW);
    for (int e = t; e < 660; e += 256) {
        const int r = e / 66, cc = e % 66;
        const int hp = ty * 8 - 1 + r;
        const int wp = cc - 1;
        uint4 v = make_uint4(0u, 0u, 0u, 0u);
        if (hp >= 0 && hp < PH && wp >= 0 && wp < PW) v = ab[hp * PW + wp];
        ha[r][cc] = v;
    }
    __syncthreads();

    // ---- per-lane activation registers: rows lr2*2 .. lr2*2+3, cols lc..lc+2 ----
    uint4 a[4][3];
    #pragma unroll
    for (int rr = 0; rr < 4; ++rr)
        #pragma unroll
        for (int cc = 0; cc < 3; ++cc)
            a[rr][cc] = ha[lr2 * 2 + rr][lc + cc];

    const int gr0 = ty * 8 + lr2 * 2;  // two output rows gr0, gr0+1
    const bool cL = (lc > 0), cR = (lc < 63);
    const bool u0 = (gr0 > 0),     d0 = (gr0 < 63);
    const bool u1 = (gr0 + 1 > 0), d1 = (gr0 + 1 < 63);

    const uint4* wb = (const uint4*)wbits_ + (size_t)branch * 128 * 9;
    const float* ws  = wscale + branch * 128;
    const float* pb0 = branch ? pb0_2  : pb0_1;
    const float* alp = branch ? alpha2 : alpha1;
    const float* pb1 = branch ? pb1_2  : pb1_1;

    const int o_beg = oh * 64, o_end = o_beg + 64;
    for (int o = o_beg; o < o_end; ++o) {
        uint4 w[9];
        #pragma unroll
        for (int tt = 0; tt < 9; ++tt) w[tt] = wb[o * 9 + tt];  // wave-uniform -> s_load

        int sum0 = 0, sum1 = 0;
        #pragma unroll
        for (int dy = 0; dy < 3; ++dy) {
            #pragma unroll
            for (int dx = 0; dx < 3; ++dx) {
                const uint4 wv = w[dy * 3 + dx];
                const int p0 = popc4(a[dy][dx],     wv);
                const int p1 = popc4(a[dy + 1][dx], wv);
                const bool col_ok = (dx == 0) ? cL : ((dx == 2) ? cR : true);
                const bool r0_ok  = (dy == 0) ? u0 : ((dy == 2) ? d0 : true);
                const bool r1_ok  = (dy == 0) ? u1 : ((dy == 2) ? d1 : true);
                sum0 += (r0_ok && col_ok) ? (128 - 2 * p0) : 0;
                sum1 += (r1_ok && col_ok) ? (128 - 2 * p1) : 0;
            }
        }

        // ---- epilogue: scale, RPReLU, residual, store ----
        const float sc   = ws[o];
        const float b0v  = pb0[o], av = alp[o], b1v = pb1[o];
        float y0 = sc * (float)sum0 + b0v;
        float y1 = sc * (float)sum1 + b0v;
        y0 = (y0 >= 0.f) ? y0 : y0 * av;
        y1 = (y1 >= 0.f) ? y1 : y1 * av;
        y0 += b1v;
        y1 += b1v;
        const size_t pbase = (size_t)(b * CH + o) * (PH * PW) + gr0 * PW + lc;
        const float r0 = pooled[pbase]      + y0;
        const float r1 = pooled[pbase + PW] + y1;
        const size_t obase = (size_t)(b * 2 * CH + branch * CH + o) * (PH * PW) + gr0 * PW + lc;
        out[obase]      = r0;
        out[obase + PW] = r1;
    }
}

extern "C" void kernel_launch(void* const* d_in, const int* in_sizes, int n_in,
                              void* d_out, int out_size, void* d_ws, size_t ws_size,
                              hipStream_t stream)
{
    const float* x      = (const float*)d_in[0];
    const float* W1     = (const float*)d_in[1];
    const float* mvk1   = (const float*)d_in[2];
    const float* mvb1   = (const float*)d_in[3];
    const float* pb0_1  = (const float*)d_in[5];
    const float* alpha1 = (const float*)d_in[6];
    const float* pb1_1  = (const float*)d_in[7];
    const float* W2     = (const float*)d_in[8];
    const float* mvk2   = (const float*)d_in[9];
    const float* mvb2   = (const float*)d_in[10];
    const float* pb0_2  = (const float*)d_in[12];
    const float* alpha2 = (const float*)d_in[13];
    const float* pb1_2  = (const float*)d_in[14];
    float* out = (float*)d_out;

    char* ws = (char*)d_ws;
    float*    pooled = (float*)ws;
    uint32_t* abits  = (uint32_t*)(ws + OFF_ABITS);
    uint32_t* wbits  = (uint32_t*)(ws + OFF_WBITS);
    float*    wscale = (float*)(ws + OFF_WSCALE);

    hipLaunchKernelGGL(pool_pack, dim3(64, 16), dim3(256), 0, stream,
                       x, mvk1, mvb1, mvk2, mvb2, pooled, abits);
    hipLaunchKernelGGL(wprep, dim3(256), dim3(64), 0, stream, W1, W2, wbits, wscale);
    hipLaunchKernelGGL(bconv_main, dim3(512), dim3(256), 0, stream,
                       abits, wbits, wscale, pooled,
                       pb0_1, alpha1, pb1_1, pb0_2, alpha2, pb1_2, out);
}

// Round 2
// 295.771 us; speedup vs baseline: 1.0950x; 1.0950x over previous
//
#include <hip/hip_runtime.h>
#include <stdint.h>

#define BATCH 16
#define CH    128
#define HIN   128
#define WIN   128
#define PH    64
#define PW    64

// d_ws layout (bytes):
//   pooled : fp16  [16][128][64][64]            = 16,777,216
//   abits  : u32   [2][16][64][64][4 words]     =  2,097,152
//   wbits  : u32   [2][128][9 taps][4 words]    =     36,864
//   wscale : float [2][128]                     =      1,024
#define OFF_ABITS  16777216u
#define OFF_WBITS  18874368u
#define OFF_WSCALE 18911232u

typedef _Float16 half2v __attribute__((ext_vector_type(2)));

__global__ __launch_bounds__(256) void pool_pack(
    const float* __restrict__ x,
    const float* __restrict__ mvk1, const float* __restrict__ mvb1,
    const float* __restrict__ mvk2, const float* __restrict__ mvb2,
    _Float16* __restrict__ pooled, uint32_t* __restrict__ abits)
{
    __shared__ float spT[64][132];          // [pixel][channel], stride 132 for b128-aligned reads
    __shared__ float thrL[2][128];
    __shared__ uint32_t flipL[2][4];
    const int b  = blockIdx.y;
    const int ph = blockIdx.x;
    const int t  = threadIdx.x;

    // ---- phase 1: 2x2 pool with float4 loads; write fp16 pooled; LDS transpose ----
    {
        const int k31 = t & 31;             // col-quad index -> output cols 2*k31, 2*k31+1
        const int c0  = (t >> 5) * 16;      // channel base
        const int pw2 = k31 * 2;
        const float* xq = x + (((size_t)b * CH) * HIN + 2 * ph) * WIN + 4 * k31;
        for (int cg = 0; cg < 16; cg += 4) {
            float q0[4], q1[4];
            #pragma unroll
            for (int u = 0; u < 4; ++u) {
                const int c = c0 + cg + u;
                const float* xr = xq + (size_t)c * (HIN * WIN);
                const float4 r0 = *(const float4*)xr;
                const float4 r1 = *(const float4*)(xr + WIN);
                q0[u] = (r0.x + r0.y + r1.x + r1.y) * 0.25f;
                q1[u] = (r0.z + r0.w + r1.z + r1.w) * 0.25f;
                union { _Float16 h[2]; uint32_t w; } pk;
                pk.h[0] = (_Float16)q0[u];
                pk.h[1] = (_Float16)q1[u];
                *(uint32_t*)(pooled + ((size_t)(b * CH + c) * (PH * PW)) + ph * PW + pw2) = pk.w;
            }
            *(float4*)&spT[pw2][c0 + cg]     = make_float4(q0[0], q0[1], q0[2], q0[3]);
            *(float4*)&spT[pw2 + 1][c0 + cg] = make_float4(q1[0], q1[1], q1[2], q1[3]);
        }
    }

    // ---- phase 1.5: per-channel threshold + flip masks (sign(p*k+b) = (p<thr)^flip) ----
    {
        const int br = t >> 7, c = t & 127;
        const float kv = (br ? mvk2 : mvk1)[c];
        const float bv = (br ? mvb2 : mvb1)[c];
        float thr;
        if (kv != 0.0f) thr = -bv / kv;
        else thr = (bv < 0.0f) ? __builtin_inff() : -__builtin_inff();
        thrL[br][c] = thr;
        const unsigned long long bal = __ballot(kv < 0.0f);
        const int lane = t & 63;
        if (lane == 0)  flipL[br][c >> 5] = (uint32_t)bal;
        if (lane == 32) flipL[br][c >> 5] = (uint32_t)(bal >> 32);
    }
    __syncthreads();

    // ---- phase 2: pack sign bits, 64 channels (2 words) per thread ----
    {
        const int wp = t & 1;               // word-pair: channels wp*64 .. wp*64+63
        const int pw = (t >> 1) & 63;       // pixel
        const int br = t >> 7;              // branch
        const float4* prow = (const float4*)&spT[pw][wp * 64];
        const float4* trow = (const float4*)&thrL[br][wp * 64];
        uint32_t bits0 = 0, bits1 = 0;
        #pragma unroll
        for (int j4 = 0; j4 < 16; ++j4) {
            const float4 p  = prow[j4];
            const float4 tv = trow[j4];
            const uint32_t m = (uint32_t)(p.x < tv.x)
                             | ((uint32_t)(p.y < tv.y) << 1)
                             | ((uint32_t)(p.z < tv.z) << 2)
                             | ((uint32_t)(p.w < tv.w) << 3);
            if (j4 < 8) bits0 |= m << (j4 * 4);
            else        bits1 |= m << ((j4 - 8) * 4);
        }
        bits0 ^= flipL[br][wp * 2];
        bits1 ^= flipL[br][wp * 2 + 1];
        uint2* ab2 = (uint2*)abits;
        ab2[((size_t)(br * BATCH + b) * (PH * PW) + ph * PW + pw) * 2 + wp] =
            make_uint2(bits0, bits1);
    }
}

__global__ __launch_bounds__(64) void wprep(
    const float* __restrict__ W1, const float* __restrict__ W2,
    uint32_t* __restrict__ wbits, float* __restrict__ wscale)
{
    const int bo = blockIdx.x;         // branch*128 + o
    const int branch = bo >> 7;
    const int o = bo & 127;
    const float* Wt = (branch ? W2 : W1) + (size_t)o * (CH * 9);
    const int t = threadIdx.x;

    float s = 0.f;
    for (int i = t; i < CH * 9; i += 64) s += fabsf(Wt[i]);
    #pragma unroll
    for (int off = 32; off >= 1; off >>= 1) s += __shfl_down(s, off);
    if (t == 0) wscale[bo] = s * (1.0f / (CH * 9));

    if (t < 36) {
        const int tap  = t >> 2;       // 0..8  (kh*3+kw)
        const int word = t & 3;        // 0..3
        uint32_t bits = 0;
        for (int j = 0; j < 32; ++j) {
            const int c = word * 32 + j;
            const float wv = Wt[c * 9 + tap];
            bits |= (wv < 0.0f ? 1u : 0u) << j;
        }
        wbits[(bo * 9 + tap) * 4 + word] = bits;
    }
}

__device__ __forceinline__ int popc4(uint4 a, uint4 w) {
    return __popc(a.x ^ w.x) + __popc(a.y ^ w.y) + __popc(a.z ^ w.z) + __popc(a.w ^ w.w);
}

__global__ __launch_bounds__(256, 8) void bconv_main(
    const uint32_t* __restrict__ abits_, const uint32_t* __restrict__ wbits_,
    const float* __restrict__ wscale, const _Float16* __restrict__ pooledH,
    const float* __restrict__ pb0_1, const float* __restrict__ alpha1, const float* __restrict__ pb1_1,
    const float* __restrict__ pb0_2, const float* __restrict__ alpha2, const float* __restrict__ pb1_2,
    float* __restrict__ out)
{
    __shared__ uint4 ha[10][66];       // activation halo, 10,560 B
    const int bid = blockIdx.x;        // ((branch*16 + b)*8 + ty)*8 + og
    const int og     = bid & 7;        // o-chunk of 16
    const int ty     = (bid >> 3) & 7;
    const int b      = (bid >> 6) & 15;
    const int branch = bid >> 10;
    const int t  = threadIdx.x;
    const int cp = t & 31;             // col pair -> cols 2cp, 2cp+1
    const int r  = t >> 5;             // 0..7
    const int gr = ty * 8 + r;         // output row

    const uint4* ab = (const uint4*)abits_ + (size_t)(branch * BATCH + b) * (PH * PW);
    for (int e = t; e < 660; e += 256) {
        const int rr = e / 66, cc = e % 66;
        const int hp = ty * 8 - 1 + rr, wp = cc - 1;
        uint4 v = make_uint4(0u, 0u, 0u, 0u);
        if (hp >= 0 && hp < PH && wp >= 0 && wp < PW) v = ab[hp * PW + wp];
        ha[rr][cc] = v;
    }
    __syncthreads();

    uint4 a[3][4];                     // rows gr-1..gr+1, halo cols 2cp..2cp+3
    #pragma unroll
    for (int i = 0; i < 3; ++i)
        #pragma unroll
        for (int j = 0; j < 4; ++j)
            a[i][j] = ha[r + i][2 * cp + j];

    const int mr0 = (gr > 0)  ? -1 : 0;
    const int mr2 = (gr < 63) ? -1 : 0;
    const int mcl = (cp > 0)  ? -1 : 0;   // out0 dx=0 validity
    const int mcr = (cp < 31) ? -1 : 0;   // out1 dx=2 validity
    const int rowsv = 1 + (gr > 0) + (gr < 63);
    const int base0 = 128 * rowsv * (2 + (cp > 0));
    const int base1 = 128 * rowsv * (2 + (cp < 31));

    const uint4* wb  = (const uint4*)wbits_ + (size_t)branch * (128 * 9);
    const float* wsv = wscale + branch * 128;
    const float* pb0 = branch ? pb0_2  : pb0_1;
    const float* alp = branch ? alpha2 : alpha1;
    const float* pb1 = branch ? pb1_2  : pb1_1;

    const _Float16* prow = pooledH + (size_t)(b * CH) * (PH * PW) + gr * PW + 2 * cp;
    float* orow = out + (size_t)(b * 2 * CH + branch * CH) * (PH * PW) + gr * PW + 2 * cp;

    const int o_beg = og * 16;
    for (int o = o_beg; o < o_beg + 16; ++o) {
        int pc0 = 0, pc1 = 0;
        #pragma unroll
        for (int dy = 0; dy < 3; ++dy) {
            const int mr = (dy == 0) ? mr0 : ((dy == 2) ? mr2 : -1);
            const uint4 w0 = wb[o * 9 + dy * 3 + 0];
            const uint4 w1 = wb[o * 9 + dy * 3 + 1];
            const uint4 w2 = wb[o * 9 + dy * 3 + 2];
            pc0 += popc4(a[dy][0], w0) & (mr & mcl);
            pc1 += popc4(a[dy][1], w0) & mr;
            pc0 += popc4(a[dy][1], w1) & mr;
            pc1 += popc4(a[dy][2], w1) & mr;
            pc0 += popc4(a[dy][2], w2) & mr;
            pc1 += popc4(a[dy][3], w2) & (mr & mcr);
        }
        const float sc = wsv[o], b0v = pb0[o], av = alp[o], b1v = pb1[o];
        float y0 = sc * (float)(base0 - 2 * pc0) + b0v;
        float y1 = sc * (float)(base1 - 2 * pc1) + b0v;
        y0 = fmaxf(y0, 0.f) + av * fminf(y0, 0.f) + b1v;
        y1 = fmaxf(y1, 0.f) + av * fminf(y1, 0.f) + b1v;
        const half2v pv = *(const half2v*)(prow + (size_t)o * (PH * PW));
        float2 st;
        st.x = (float)pv.x + y0;
        st.y = (float)pv.y + y1;
        *(float2*)(orow + (size_t)o * (PH * PW)) = st;
    }
}

extern "C" void kernel_launch(void* const* d_in, const int* in_sizes, int n_in,
                              void* d_out, int out_size, void* d_ws, size_t ws_size,
                              hipStream_t stream)
{
    const float* x      = (const float*)d_in[0];
    const float* W1     = (const float*)d_in[1];
    const float* mvk1   = (const float*)d_in[2];
    const float* mvb1   = (const float*)d_in[3];
    const float* pb0_1  = (const float*)d_in[5];
    const float* alpha1 = (const float*)d_in[6];
    const float* pb1_1  = (const float*)d_in[7];
    const float* W2     = (const float*)d_in[8];
    const float* mvk2   = (const float*)d_in[9];
    const float* mvb2   = (const float*)d_in[10];
    const float* pb0_2  = (const float*)d_in[12];
    const float* alpha2 = (const float*)d_in[13];
    const float* pb1_2  = (const float*)d_in[14];
    float* out = (float*)d_out;

    char* ws = (char*)d_ws;
    _Float16* pooled = (_Float16*)ws;
    uint32_t* abits  = (uint32_t*)(ws + OFF_ABITS);
    uint32_t* wbits  = (uint32_t*)(ws + OFF_WBITS);
    float*    wscale = (float*)(ws + OFF_WSCALE);

    hipLaunchKernelGGL(pool_pack, dim3(64, 16), dim3(256), 0, stream,
                       x, mvk1, mvb1, mvk2, mvb2, pooled, abits);
    hipLaunchKernelGGL(wprep, dim3(256), dim3(64), 0, stream, W1, W2, wbits, wscale);
    hipLaunchKernelGGL(bconv_main, dim3(2048), dim3(256), 0, stream,
                       abits, wbits, wscale, pooled,
                       pb0_1, alpha1, pb1_1, pb0_2, alpha2, pb1_2, out);
}

// Round 3
// 289.802 us; speedup vs baseline: 1.1175x; 1.0206x over previous
//
#include <hip/hip_runtime.h>
#include <stdint.h>

#define BATCH 16
#define CH    128
#define HIN   128
#define WIN   128
#define PH    64
#define PW    64

// d_ws layout (bytes):
//   pooled : fp16  [16][128][64][64]            = 16,777,216
//   abits  : u32   [2][16][64][64][4 words]     =  2,097,152
//   wbits  : u32   [2][128][9 taps][4 words]    =     36,864
//   wscale : float [2][128]                     =      1,024
//   wcorr  : int32 [2][128][8]                  =      8,192
#define OFF_ABITS  16777216u
#define OFF_WBITS  18874368u
#define OFF_WSCALE 18911232u
#define OFF_WCORR  18912256u

typedef _Float16 half2v __attribute__((ext_vector_type(2)));

__global__ __launch_bounds__(256) void pool_pack(
    const float* __restrict__ x,
    const float* __restrict__ mvk1, const float* __restrict__ mvb1,
    const float* __restrict__ mvk2, const float* __restrict__ mvb2,
    _Float16* __restrict__ pooled, uint32_t* __restrict__ abits)
{
    __shared__ float kL[2][128], bL[2][128];
    __shared__ unsigned short sb[2][64][8];   // [branch][pixel][group-of-16ch]
    const int b  = blockIdx.y;
    const int ph = blockIdx.x;
    const int t  = threadIdx.x;

    // phase 0: stage per-channel affine params
    {
        const int br = t >> 7, c = t & 127;
        kL[br][c] = (br ? mvk2 : mvk1)[c];
        bL[br][c] = (br ? mvb2 : mvb1)[c];
    }
    __syncthreads();

    // phase 1: 2x2 pool (float4 loads), fp16 pooled store, register bit-pack
    const int k31 = t & 31;            // -> output cols 2*k31, 2*k31+1
    const int g   = t >> 5;            // channel group: channels g*16 .. g*16+15
    const int pw2 = 2 * k31;
    const float* xq = x + (((size_t)b * CH) * HIN + 2 * ph) * WIN + 4 * k31;
    uint32_t m00 = 0, m01 = 0, m10 = 0, m11 = 0;  // [branch][pixel]
    #pragma unroll
    for (int u = 0; u < 16; ++u) {
        const int c = g * 16 + u;
        const float* xr = xq + (size_t)c * (HIN * WIN);
        const float4 r0 = *(const float4*)xr;
        const float4 r1 = *(const float4*)(xr + WIN);
        const float q0 = (r0.x + r0.y + r1.x + r1.y) * 0.25f;
        const float q1 = (r0.z + r0.w + r1.z + r1.w) * 0.25f;
        union { _Float16 h[2]; uint32_t w; } pk;
        pk.h[0] = (_Float16)q0;
        pk.h[1] = (_Float16)q1;
        *(uint32_t*)(pooled + ((size_t)(b * CH + c) * (PH * PW)) + ph * PW + pw2) = pk.w;
        const float k0 = kL[0][c], b0 = bL[0][c];
        const float k1 = kL[1][c], b1 = bL[1][c];
        m00 |= (uint32_t)(fmaf(q0, k0, b0) < 0.0f) << u;
        m01 |= (uint32_t)(fmaf(q1, k0, b0) < 0.0f) << u;
        m10 |= (uint32_t)(fmaf(q0, k1, b1) < 0.0f) << u;
        m11 |= (uint32_t)(fmaf(q1, k1, b1) < 0.0f) << u;
    }
    sb[0][pw2][g]     = (unsigned short)m00;
    sb[0][pw2 + 1][g] = (unsigned short)m01;
    sb[1][pw2][g]     = (unsigned short)m10;
    sb[1][pw2 + 1][g] = (unsigned short)m11;
    __syncthreads();

    // phase 2: assemble words, write uint2 (channels wp*64 .. wp*64+63)
    {
        const int wp = t & 1;
        const int px = (t >> 1) & 63;
        const int br = t >> 7;
        const unsigned short* h = &sb[br][px][wp * 4];
        uint2 v;
        v.x = (uint32_t)h[0] | ((uint32_t)h[1] << 16);
        v.y = (uint32_t)h[2] | ((uint32_t)h[3] << 16);
        ((uint2*)abits)[((size_t)(br * BATCH + b) * (PH * PW) + ph * PW + px) * 2 + wp] = v;
    }
}

__global__ __launch_bounds__(64) void wprep(
    const float* __restrict__ W1, const float* __restrict__ W2,
    uint32_t* __restrict__ wbits, float* __restrict__ wscale,
    int* __restrict__ wcorr)
{
    __shared__ uint32_t swb[9][4];
    __shared__ int tpv[9];             // 2*popc(tap) - 128
    const int bo = blockIdx.x;         // branch*128 + o
    const int branch = bo >> 7;
    const int o = bo & 127;
    const float* Wt = (branch ? W2 : W1) + (size_t)o * (CH * 9);
    const int t = threadIdx.x;

    float s = 0.f;
    for (int i = t; i < CH * 9; i += 64) s += fabsf(Wt[i]);
    #pragma unroll
    for (int off = 32; off >= 1; off >>= 1) s += __shfl_down(s, off);
    if (t == 0) wscale[bo] = s * (1.0f / (CH * 9));

    if (t < 36) {
        const int tap  = t >> 2;       // kh*3+kw
        const int word = t & 3;
        uint32_t bits = 0;
        for (int j = 0; j < 32; ++j) {
            const float wv = Wt[(word * 32 + j) * 9 + tap];
            bits |= (wv < 0.0f ? 1u : 0u) << j;
        }
        wbits[(bo * 9 + tap) * 4 + word] = bits;
        swb[tap][word] = bits;
    }
    __syncthreads();
    if (t < 9)
        tpv[t] = 2 * (__popc(swb[t][0]) + __popc(swb[t][1]) +
                      __popc(swb[t][2]) + __popc(swb[t][3])) - 128;
    __syncthreads();
    if (t == 0) {
        int* wc = wcorr + bo * 8;
        wc[0] = tpv[0] + tpv[1] + tpv[2];   // cr0: top row invalid
        wc[1] = tpv[6] + tpv[7] + tpv[8];   // cr2: bottom row invalid
        wc[2] = tpv[0] + tpv[3] + tpv[6];   // cc0: left col invalid
        wc[3] = tpv[2] + tpv[5] + tpv[8];   // cc2: right col invalid
        wc[4] = tpv[0];                     // k00
        wc[5] = tpv[2];                     // k02
        wc[6] = tpv[6];                     // k20
        wc[7] = tpv[8];                     // k22
    }
}

__device__ __forceinline__ int bcnt_acc(uint32_t xv, int acc) {
    int d;
    asm("v_bcnt_u32_b32 %0, %1, %2" : "=v"(d) : "v"(xv), "v"(acc));
    return d;
}
__device__ __forceinline__ int xacc4(uint4 a, uint4 w, int acc) {
    acc = bcnt_acc(a.x ^ w.x, acc);
    acc = bcnt_acc(a.y ^ w.y, acc);
    acc = bcnt_acc(a.z ^ w.z, acc);
    acc = bcnt_acc(a.w ^ w.w, acc);
    return acc;
}

__global__ __launch_bounds__(256, 8) void bconv_main(
    const uint32_t* __restrict__ abits_, const uint32_t* __restrict__ wbits_,
    const float* __restrict__ wscale, const int* __restrict__ wcorr,
    const _Float16* __restrict__ pooledH,
    const float* __restrict__ pb0_1, const float* __restrict__ alpha1, const float* __restrict__ pb1_1,
    const float* __restrict__ pb0_2, const float* __restrict__ alpha2, const float* __restrict__ pb1_2,
    float* __restrict__ out)
{
    __shared__ uint4 ha[10][66];       // activation halo, 10,560 B
    const int bid = blockIdx.x;        // ((branch*16 + b)*8 + ty)*8 + og
    const int og     = bid & 7;        // o-chunk of 16
    const int ty     = (bid >> 3) & 7;
    const int b      = (bid >> 6) & 15;
    const int branch = bid >> 10;
    const int t  = threadIdx.x;
    const int cp = t & 31;             // col pair -> cols 2cp, 2cp+1
    const int r  = t >> 5;             // 0..7
    const int gr = ty * 8 + r;         // output row

    const uint4* ab = (const uint4*)abits_ + (size_t)(branch * BATCH + b) * (PH * PW);
    for (int e = t; e < 660; e += 256) {
        const int rr = e / 66, cc = e % 66;
        const int hp = ty * 8 - 1 + rr, wp = cc - 1;
        uint4 v = make_uint4(0u, 0u, 0u, 0u);
        if (hp >= 0 && hp < PH && wp >= 0 && wp < PW) v = ab[hp * PW + wp];
        ha[rr][cc] = v;
    }
    __syncthreads();

    uint4 a[3][4];                     // rows gr-1..gr+1, halo cols 2cp..2cp+3
    #pragma unroll
    for (int i = 0; i < 3; ++i)
        #pragma unroll
        for (int j = 0; j < 4; ++j)
            a[i][j] = ha[r + i][2 * cp + j];

    const bool fr0 = (gr == 0), fr2 = (gr == 63);
    const bool fc0 = (cp == 0), fc2 = (cp == 31);   // out0 left edge / out1 right edge

    const uint4* wb  = (const uint4*)wbits_ + (size_t)branch * (128 * 9);
    const int*   wcb = wcorr + branch * (128 * 8);
    const float* wsv = wscale + branch * 128;
    const float* pb0 = branch ? pb0_2  : pb0_1;
    const float* alp = branch ? alpha2 : alpha1;
    const float* pb1 = branch ? pb1_2  : pb1_1;

    const _Float16* prow = pooledH + (size_t)(b * CH) * (PH * PW) + gr * PW + 2 * cp;
    float* orow = out + (size_t)(b * 2 * CH + branch * CH) * (PH * PW) + gr * PW + 2 * cp;

    const int o_beg = og * 16;
    for (int o = o_beg; o < o_beg + 16; ++o) {
        int pc0 = 0, pc1 = 0;
        #pragma unroll
        for (int dy = 0; dy < 3; ++dy) {
            const uint4 w0 = wb[o * 9 + dy * 3 + 0];
            const uint4 w1 = wb[o * 9 + dy * 3 + 1];
            const uint4 w2 = wb[o * 9 + dy * 3 + 2];
            pc0 = xacc4(a[dy][0], w0, pc0);
            pc1 = xacc4(a[dy][1], w0, pc1);
            pc0 = xacc4(a[dy][1], w1, pc0);
            pc1 = xacc4(a[dy][2], w1, pc1);
            pc0 = xacc4(a[dy][2], w2, pc0);
            pc1 = xacc4(a[dy][3], w2, pc1);
        }
        // border correction: S = 1152 + corr - 2*pc
        const int4 wcA = *(const int4*)(wcb + o * 8);
        const int4 wcB = *(const int4*)(wcb + o * 8 + 4);
        const int baser = (fr0 ? wcA.x : 0) + (fr2 ? wcA.y : 0);
        const int cc0e  = wcA.z - (fr0 ? wcB.x : 0) - (fr2 ? wcB.z : 0);
        const int cc2e  = wcA.w - (fr0 ? wcB.y : 0) - (fr2 ? wcB.w : 0);
        const int S0 = 1152 + baser + (fc0 ? cc0e : 0) - 2 * pc0;
        const int S1 = 1152 + baser + (fc2 ? cc2e : 0) - 2 * pc1;

        const float sc = wsv[o], b0v = pb0[o], av = alp[o], b1v = pb1[o];
        float y0 = sc * (float)S0 + b0v;
        float y1 = sc * (float)S1 + b0v;
        y0 = fmaxf(y0, 0.f) + av * fminf(y0, 0.f) + b1v;
        y1 = fmaxf(y1, 0.f) + av * fminf(y1, 0.f) + b1v;
        const half2v pv = *(const half2v*)(prow + (size_t)o * (PH * PW));
        float2 st;
        st.x = (float)pv.x + y0;
        st.y = (float)pv.y + y1;
        *(float2*)(orow + (size_t)o * (PH * PW)) = st;
    }
}

extern "C" void kernel_launch(void* const* d_in, const int* in_sizes, int n_in,
                              void* d_out, int out_size, void* d_ws, size_t ws_size,
                              hipStream_t stream)
{
    const float* x      = (const float*)d_in[0];
    const float* W1     = (const float*)d_in[1];
    const float* mvk1   = (const float*)d_in[2];
    const float* mvb1   = (const float*)d_in[3];
    const float* pb0_1  = (const float*)d_in[5];
    const float* alpha1 = (const float*)d_in[6];
    const float* pb1_1  = (const float*)d_in[7];
    const float* W2     = (const float*)d_in[8];
    const float* mvk2   = (const float*)d_in[9];
    const float* mvb2   = (const float*)d_in[10];
    const float* pb0_2  = (const float*)d_in[12];
    const float* alpha2 = (const float*)d_in[13];
    const float* pb1_2  = (const float*)d_in[14];
    float* out = (float*)d_out;

    char* ws = (char*)d_ws;
    _Float16* pooled = (_Float16*)ws;
    uint32_t* abits  = (uint32_t*)(ws + OFF_ABITS);
    uint32_t* wbits  = (uint32_t*)(ws + OFF_WBITS);
    float*    wscale = (float*)(ws + OFF_WSCALE);
    int*      wcorr  = (int*)(ws + OFF_WCORR);

    hipLaunchKernelGGL(wprep, dim3(256), dim3(64), 0, stream, W1, W2, wbits, wscale, wcorr);
    hipLaunchKernelGGL(pool_pack, dim3(64, 16), dim3(256), 0, stream,
                       x, mvk1, mvb1, mvk2, mvb2, pooled, abits);
    hipLaunchKernelGGL(bconv_main, dim3(2048), dim3(256), 0, stream,
                       abits, wbits, wscale, wcorr, pooled,
                       pb0_1, alpha1, pb1_1, pb0_2, alpha2, pb1_2, out);
}

// Round 5
// 274.978 us; speedup vs baseline: 1.1778x; 1.0539x over previous
//
#include <hip/hip_runtime.h>
#include <stdint.h>

#define BATCH 16
#define CH    128
#define HIN   128
#define WIN   128
#define PH    64
#define PW    64
#define PADW  66            // padded abits row length (uint4 units)
#define IMGS  (PADW * PADW) // 4356 uint4 per (branch,b) image

// d_ws layout (bytes):
//   pooled    : fp16 [16][128][64][64]          = 16,777,216
//   abits_pad : uint4[2][16][66][66]            =  2,230,272  (zero guard band)
//   wbits     : u32  [2][128][9][4]             =     36,864
//   wscale    : f32  [2][128]                   =      1,024
//   wcorr     : i32  [2][128][8]                =      8,192
#define OFF_ABITS  16777216u
#define OFF_WBITS  19007488u
#define OFF_WSCALE 19044352u
#define OFF_WCORR  19045376u

typedef _Float16 half2v __attribute__((ext_vector_type(2)));
typedef float    fvec4  __attribute__((ext_vector_type(4)));
typedef float    fvec2  __attribute__((ext_vector_type(2)));

__global__ __launch_bounds__(256) void pool_pack(
    const float* __restrict__ x,
    const float* __restrict__ mvk1, const float* __restrict__ mvb1,
    const float* __restrict__ mvk2, const float* __restrict__ mvb2,
    _Float16* __restrict__ pooled, uint32_t* __restrict__ abits)
{
    __shared__ float kL[2][128], bL[2][128];
    __shared__ unsigned short sb[2][64][8];   // [branch][pixel][group-of-16ch]
    const int b  = blockIdx.y;
    const int ph = blockIdx.x;
    const int t  = threadIdx.x;

    // phase 0: stage per-channel affine params
    {
        const int br = t >> 7, c = t & 127;
        kL[br][c] = (br ? mvk2 : mvk1)[c];
        bL[br][c] = (br ? mvb2 : mvb1)[c];
    }
    __syncthreads();

    // phase 1: 2x2 pool (NT float4 loads), fp16 pooled store, register bit-pack
    const int k31 = t & 31;            // -> output cols 2*k31, 2*k31+1
    const int g   = t >> 5;            // channel group: channels g*16 .. g*16+15
    const int pw2 = 2 * k31;
    const float* xq = x + (((size_t)b * CH) * HIN + 2 * ph) * WIN + 4 * k31;
    uint32_t m00 = 0, m01 = 0, m10 = 0, m11 = 0;  // [branch][pixel]
    #pragma unroll
    for (int u = 0; u < 16; ++u) {
        const int c = g * 16 + u;
        const float* xr = xq + (size_t)c * (HIN * WIN);
        const fvec4 r0 = __builtin_nontemporal_load((const fvec4*)xr);
        const fvec4 r1 = __builtin_nontemporal_load((const fvec4*)(xr + WIN));
        const float q0 = (r0.x + r0.y + r1.x + r1.y) * 0.25f;
        const float q1 = (r0.z + r0.w + r1.z + r1.w) * 0.25f;
        union { _Float16 h[2]; uint32_t w; } pk;
        pk.h[0] = (_Float16)q0;
        pk.h[1] = (_Float16)q1;
        *(uint32_t*)(pooled + ((size_t)(b * CH + c) * (PH * PW)) + ph * PW + pw2) = pk.w;
        const float k0 = kL[0][c], b0 = bL[0][c];
        const float k1 = kL[1][c], b1 = bL[1][c];
        m00 |= (uint32_t)(fmaf(q0, k0, b0) < 0.0f) << u;
        m01 |= (uint32_t)(fmaf(q1, k0, b0) < 0.0f) << u;
        m10 |= (uint32_t)(fmaf(q0, k1, b1) < 0.0f) << u;
        m11 |= (uint32_t)(fmaf(q1, k1, b1) < 0.0f) << u;
    }
    sb[0][pw2][g]     = (unsigned short)m00;
    sb[0][pw2 + 1][g] = (unsigned short)m01;
    sb[1][pw2][g]     = (unsigned short)m10;
    sb[1][pw2 + 1][g] = (unsigned short)m11;
    __syncthreads();

    // phase 2: assemble words, write uint2 into PADDED layout (+1 row, +1 col)
    {
        const int wp = t & 1;
        const int px = (t >> 1) & 63;
        const int br = t >> 7;
        const unsigned short* h = &sb[br][px][wp * 4];
        uint2 v;
        v.x = (uint32_t)h[0] | ((uint32_t)h[1] << 16);
        v.y = (uint32_t)h[2] | ((uint32_t)h[3] << 16);
        ((uint2*)abits)[((size_t)(br * BATCH + b) * IMGS + (ph + 1) * PADW + px + 1) * 2 + wp] = v;
    }
}

__global__ __launch_bounds__(64) void wprep(
    const float* __restrict__ W1, const float* __restrict__ W2,
    uint32_t* __restrict__ wbits, float* __restrict__ wscale,
    int* __restrict__ wcorr, uint32_t* __restrict__ abits)
{
    const int bid = blockIdx.x;
    const int t = threadIdx.x;

    if (bid >= 256) {
        // ---- zero the abits guard band: 2 blocks per (branch,b) image ----
        const int img  = (bid - 256) >> 1;
        const int half = bid & 1;
        uint4* base = (uint4*)abits + (size_t)img * IMGS;
        const uint4 z = make_uint4(0u, 0u, 0u, 0u);
        for (int e = t; e < 130; e += 64) {
            int rr, cc;
            if (half == 0) { if (e < 66) { rr = 0;  cc = e; } else { rr = e - 65; cc = 0; } }
            else           { if (e < 66) { rr = 65; cc = e; } else { rr = e - 65; cc = 65; } }
            base[rr * PADW + cc] = z;
        }
        return;
    }

    __shared__ uint32_t swb[9][4];
    __shared__ int tpv[9];             // 2*popc(tap) - 128
    const int bo = bid;                // branch*128 + o
    const int branch = bo >> 7;
    const int o = bo & 127;
    const float* Wt = (branch ? W2 : W1) + (size_t)o * (CH * 9);

    float s = 0.f;
    for (int i = t; i < CH * 9; i += 64) s += fabsf(Wt[i]);
    #pragma unroll
    for (int off = 32; off >= 1; off >>= 1) s += __shfl_down(s, off);
    if (t == 0) wscale[bo] = s * (1.0f / (CH * 9));

    if (t < 36) {
        const int tap  = t >> 2;       // kh*3+kw
        const int word = t & 3;
        uint32_t bits = 0;
        for (int j = 0; j < 32; ++j) {
            const float wv = Wt[(word * 32 + j) * 9 + tap];
            bits |= (wv < 0.0f ? 1u : 0u) << j;
        }
        wbits[(bo * 9 + tap) * 4 + word] = bits;
        swb[tap][word] = bits;
    }
    __syncthreads();
    if (t < 9)
        tpv[t] = 2 * (__popc(swb[t][0]) + __popc(swb[t][1]) +
                      __popc(swb[t][2]) + __popc(swb[t][3])) - 128;
    __syncthreads();
    if (t == 0) {
        int* wc = wcorr + bo * 8;
        wc[0] = tpv[0] + tpv[1] + tpv[2];   // cr0: top row invalid
        wc[1] = tpv[6] + tpv[7] + tpv[8];   // cr2: bottom row invalid
        wc[2] = tpv[0] + tpv[3] + tpv[6];   // cc0: left col invalid
        wc[3] = tpv[2] + tpv[5] + tpv[8];   // cc2: right col invalid
        wc[4] = tpv[0];                     // k00
        wc[5] = tpv[2];                     // k02
        wc[6] = tpv[6];                     // k20
        wc[7] = tpv[8];                     // k22
    }
}

__device__ __forceinline__ int bcnt_acc(uint32_t xv, int acc) {
    int d;
    asm("v_bcnt_u32_b32 %0, %1, %2" : "=v"(d) : "v"(xv), "v"(acc));
    return d;
}
__device__ __forceinline__ int xacc4(uint4 a, uint4 w, int acc) {
    acc = bcnt_acc(a.x ^ w.x, acc);
    acc = bcnt_acc(a.y ^ w.y, acc);
    acc = bcnt_acc(a.z ^ w.z, acc);
    acc = bcnt_acc(a.w ^ w.w, acc);
    return acc;
}

__global__ __launch_bounds__(256, 8) void bconv_main(
    const uint32_t* __restrict__ abits_, const uint32_t* __restrict__ wbits_,
    const float* __restrict__ wscale, const int* __restrict__ wcorr,
    const _Float16* __restrict__ pooledH,
    const float* __restrict__ pb0_1, const float* __restrict__ alpha1, const float* __restrict__ pb1_1,
    const float* __restrict__ pb0_2, const float* __restrict__ alpha2, const float* __restrict__ pb1_2,
    float* __restrict__ out)
{
    const int bid = blockIdx.x;        // ((branch*16 + b)*8 + ty)*8 + og
    const int og     = bid & 7;        // o-chunk of 16
    const int ty     = (bid >> 3) & 7;
    const int b      = (bid >> 6) & 15;
    const int branch = bid >> 10;
    const int t  = threadIdx.x;
    const int cp = t & 31;             // col pair -> cols 2cp, 2cp+1
    const int r  = t >> 5;             // 0..7
    const int gr = ty * 8 + r;         // output row

    // ---- direct global loads of the 12 activation halo words (padded, zero guard) ----
    const uint4* ab = (const uint4*)abits_ + (size_t)(branch * BATCH + b) * IMGS
                    + (size_t)gr * PADW + 2 * cp;   // padded rows gr..gr+2, cols 2cp..2cp+3
    uint4 a[3][4];
    #pragma unroll
    for (int i = 0; i < 3; ++i)
        #pragma unroll
        for (int j = 0; j < 4; ++j)
            a[i][j] = ab[i * PADW + j];

    const bool fr0 = (gr == 0), fr2 = (gr == 63);
    const bool fc0 = (cp == 0), fc2 = (cp == 31);   // out0 left edge / out1 right edge

    const uint4* wb  = (const uint4*)wbits_ + (size_t)branch * (128 * 9);
    const int*   wcb = wcorr + branch * (128 * 8);
    const float* wsv = wscale + branch * 128;
    const float* pb0 = branch ? pb0_2  : pb0_1;
    const float* alp = branch ? alpha2 : alpha1;
    const float* pb1 = branch ? pb1_2  : pb1_1;

    const _Float16* prow = pooledH + (size_t)(b * CH) * (PH * PW) + gr * PW + 2 * cp;
    float* orow = out + (size_t)(b * 2 * CH + branch * CH) * (PH * PW) + gr * PW + 2 * cp;

    const int o_beg = og * 16;
    #pragma unroll 4
    for (int o = o_beg; o < o_beg + 16; ++o) {
        int pc0 = 0, pc1 = 0;
        #pragma unroll
        for (int dy = 0; dy < 3; ++dy) {
            const uint4 w0 = wb[o * 9 + dy * 3 + 0];
            const uint4 w1 = wb[o * 9 + dy * 3 + 1];
            const uint4 w2 = wb[o * 9 + dy * 3 + 2];
            pc0 = xacc4(a[dy][0], w0, pc0);
            pc1 = xacc4(a[dy][1], w0, pc1);
            pc0 = xacc4(a[dy][1], w1, pc0);
            pc1 = xacc4(a[dy][2], w1, pc1);
            pc0 = xacc4(a[dy][2], w2, pc0);
            pc1 = xacc4(a[dy][3], w2, pc1);
        }
        // border correction: S = 1152 + corr - 2*pc   (guard band a=0 -> tap adds popc(w))
        const int4 wcA = *(const int4*)(wcb + o * 8);
        const int4 wcB = *(const int4*)(wcb + o * 8 + 4);
        const int baser = (fr0 ? wcA.x : 0) + (fr2 ? wcA.y : 0);
        const int cc0e  = wcA.z - (fr0 ? wcB.x : 0) - (fr2 ? wcB.z : 0);
        const int cc2e  = wcA.w - (fr0 ? wcB.y : 0) - (fr2 ? wcB.w : 0);
        const int S0 = 1152 + baser + (fc0 ? cc0e : 0) - 2 * pc0;
        const int S1 = 1152 + baser + (fc2 ? cc2e : 0) - 2 * pc1;

        const float sc = wsv[o], b0v = pb0[o], av = alp[o], b1v = pb1[o];
        float y0 = sc * (float)S0 + b0v;
        float y1 = sc * (float)S1 + b0v;
        y0 = fmaxf(y0, 0.f) + av * fminf(y0, 0.f) + b1v;
        y1 = fmaxf(y1, 0.f) + av * fminf(y1, 0.f) + b1v;
        const half2v pv = *(const half2v*)(prow + (size_t)o * (PH * PW));
        fvec2 st;
        st.x = (float)pv.x + y0;
        st.y = (float)pv.y + y1;
        __builtin_nontemporal_store(st, (fvec2*)(orow + (size_t)o * (PH * PW)));
    }
}

extern "C" void kernel_launch(void* const* d_in, const int* in_sizes, int n_in,
                              void* d_out, int out_size, void* d_ws, size_t ws_size,
                              hipStream_t stream)
{
    const float* x      = (const float*)d_in[0];
    const float* W1     = (const float*)d_in[1];
    const float* mvk1   = (const float*)d_in[2];
    const float* mvb1   = (const float*)d_in[3];
    const float* pb0_1  = (const float*)d_in[5];
    const float* alpha1 = (const float*)d_in[6];
    const float* pb1_1  = (const float*)d_in[7];
    const float* W2     = (const float*)d_in[8];
    const float* mvk2   = (const float*)d_in[9];
    const float* mvb2   = (const float*)d_in[10];
    const float* pb0_2  = (const float*)d_in[12];
    const float* alpha2 = (const float*)d_in[13];
    const float* pb1_2  = (const float*)d_in[14];
    float* out = (float*)d_out;

    char* ws = (char*)d_ws;
    _Float16* pooled = (_Float16*)ws;
    uint32_t* abits  = (uint32_t*)(ws + OFF_ABITS);
    uint32_t* wbits  = (uint32_t*)(ws + OFF_WBITS);
    float*    wscale = (float*)(ws + OFF_WSCALE);
    int*      wcorr  = (int*)(ws + OFF_WCORR);

    hipLaunchKernelGGL(wprep, dim3(320), dim3(64), 0, stream,
                       W1, W2, wbits, wscale, wcorr, abits);
    hipLaunchKernelGGL(pool_pack, dim3(64, 16), dim3(256), 0, stream,
                       x, mvk1, mvb1, mvk2, mvb2, pooled, abits);
    hipLaunchKernelGGL(bconv_main, dim3(2048), dim3(256), 0, stream,
                       abits, wbits, wscale, wcorr, pooled,
                       pb0_1, alpha1, pb1_1, pb0_2, alpha2, pb1_2, out);
}

// Round 8
// 267.212 us; speedup vs baseline: 1.2120x; 1.0291x over previous
//
#include <hip/hip_runtime.h>
#include <stdint.h>

#define BATCH 16
#define CH    128
#define HIN   128
#define WIN   128
#define PH    64
#define PW    64
#define PADW  66            // padded abits row length (uint4 units)
#define IMGS  (PADW * PADW) // 4356 uint4 per (branch,b) image

// d_ws layout (bytes):
//   pooled    : fp16 [16][128][64][64]          = 16,777,216
//   abits_pad : uint4[2][16][66][66]            =  2,230,272  (zero guard band)
//   wrec      : u32  [256][48]                  =     49,152
//               per (branch*128+o): w[36] (tap-major), corr[8], {sc,pb0,alpha,pb1}
#define OFF_ABITS  16777216u
#define OFF_WREC   19007488u

typedef _Float16 half2v __attribute__((ext_vector_type(2)));
typedef float    fvec4  __attribute__((ext_vector_type(4)));
typedef float    fvec2  __attribute__((ext_vector_type(2)));

// Fused: pool+pack (blocks 0..1023), weight-record prep (1024..1279, LDS-based
// aggregation — cross-lane reads in divergent control are a miscompile trap),
// abits guard-band zero (1280..1311).
__global__ __launch_bounds__(256) void prep_fused(
    const float* __restrict__ x,
    const float* __restrict__ mvk1, const float* __restrict__ mvb1,
    const float* __restrict__ mvk2, const float* __restrict__ mvb2,
    const float* __restrict__ W1,   const float* __restrict__ W2,
    const float* __restrict__ pb0_1, const float* __restrict__ alpha1, const float* __restrict__ pb1_1,
    const float* __restrict__ pb0_2, const float* __restrict__ alpha2, const float* __restrict__ pb1_2,
    _Float16* __restrict__ pooled, uint32_t* __restrict__ abits,
    uint32_t* __restrict__ wrec)
{
    const int bid = blockIdx.x;
    const int t   = threadIdx.x;

    if (bid >= 1280) {
        // ---- abits guard band zero: 1 block per (branch,b) image ----
        const int img = bid - 1280;
        uint4* base = (uint4*)abits + (size_t)img * IMGS;
        const uint4 z = make_uint4(0u, 0u, 0u, 0u);
        for (int e = t; e < 260; e += 256) {
            int rr, cc;
            if (e < 130) { if (e < 66) { rr = 0;  cc = e; } else { rr = e - 65; cc = 0;  } }
            else { const int e2 = e - 130;
                   if (e2 < 66) { rr = 65; cc = e2; } else { rr = e2 - 65; cc = 65; } }
            base[rr * PADW + cc] = z;
        }
        return;
    }

    if (bid >= 1024) {
        // ---- weight record prep (LDS aggregation, round-5-proven pattern) ----
        __shared__ uint32_t swb[9][4];
        __shared__ int tpv9[9];
        const int bo = bid - 1024;         // branch*128 + o
        const int branch = bo >> 7;
        const int o = bo & 127;
        const float* Wt = (branch ? W2 : W1) + (size_t)o * (CH * 9);
        uint32_t* rec = wrec + (size_t)bo * 48;

        float s = 0.f;
        if (t < 64) {
            // abs-mean scale (wave 0 only)
            for (int i = t; i < CH * 9; i += 64) s += fabsf(Wt[i]);
            #pragma unroll
            for (int off = 32; off >= 1; off >>= 1) s += __shfl_down(s, off);

            // bit-pack: lane t<36 -> tap t>>2, word t&3
            if (t < 36) {
                const int tap  = t >> 2;
                const int word = t & 3;
                uint32_t bits = 0;
                for (int j = 0; j < 32; ++j) {
                    const float wv = Wt[(word * 32 + j) * 9 + tap];
                    bits |= (wv < 0.0f ? 1u : 0u) << j;
                }
                rec[t] = bits;             // w[36], tap-major
                swb[tap][word] = bits;
            }
        }
        __syncthreads();
        if (t < 9)
            tpv9[t] = 2 * (__popc(swb[t][0]) + __popc(swb[t][1]) +
                           __popc(swb[t][2]) + __popc(swb[t][3])) - 128;
        __syncthreads();
        if (t == 0) {
            int* corr = (int*)(rec + 36);
            corr[0] = tpv9[0] + tpv9[1] + tpv9[2];   // top row invalid
            corr[1] = tpv9[6] + tpv9[7] + tpv9[8];   // bottom row invalid
            corr[2] = tpv9[0] + tpv9[3] + tpv9[6];   // left col invalid
            corr[3] = tpv9[2] + tpv9[5] + tpv9[8];   // right col invalid
            corr[4] = tpv9[0];  corr[5] = tpv9[2];
            corr[6] = tpv9[6];  corr[7] = tpv9[8];
            float* fs = (float*)(rec + 44);
            fs[0] = s * (1.0f / (CH * 9));
            fs[1] = (branch ? pb0_2  : pb0_1)[o];
            fs[2] = (branch ? alpha2 : alpha1)[o];
            fs[3] = (branch ? pb1_2  : pb1_1)[o];
        }
        return;
    }

    // ---- pool + activation bit-pack ----
    __shared__ float kL[2][128], bL[2][128];
    __shared__ unsigned short sb[2][64][8];   // [branch][pixel][group-of-16ch]
    const int b  = bid >> 6;
    const int ph = bid & 63;

    {
        const int br = t >> 7, c = t & 127;
        kL[br][c] = (br ? mvk2 : mvk1)[c];
        bL[br][c] = (br ? mvb2 : mvb1)[c];
    }
    __syncthreads();

    const int k31 = t & 31;            // -> output cols 2*k31, 2*k31+1
    const int g   = t >> 5;            // channel group: channels g*16 .. g*16+15
    const int pw2 = 2 * k31;
    const float* xq = x + (((size_t)b * CH) * HIN + 2 * ph) * WIN + 4 * k31;
    uint32_t m00 = 0, m01 = 0, m10 = 0, m11 = 0;  // [branch][pixel]
    #pragma unroll
    for (int u = 0; u < 16; ++u) {
        const int c = g * 16 + u;
        const float* xr = xq + (size_t)c * (HIN * WIN);
        const fvec4 r0 = __builtin_nontemporal_load((const fvec4*)xr);
        const fvec4 r1 = __builtin_nontemporal_load((const fvec4*)(xr + WIN));
        const float q0 = (r0.x + r0.y + r1.x + r1.y) * 0.25f;
        const float q1 = (r0.z + r0.w + r1.z + r1.w) * 0.25f;
        union { _Float16 h[2]; uint32_t w; } pk;
        pk.h[0] = (_Float16)q0;
        pk.h[1] = (_Float16)q1;
        *(uint32_t*)(pooled + ((size_t)(b * CH + c) * (PH * PW)) + ph * PW + pw2) = pk.w;
        const float k0 = kL[0][c], b0 = bL[0][c];
        const float k1 = kL[1][c], b1 = bL[1][c];
        m00 |= (uint32_t)(fmaf(q0, k0, b0) < 0.0f) << u;
        m01 |= (uint32_t)(fmaf(q1, k0, b0) < 0.0f) << u;
        m10 |= (uint32_t)(fmaf(q0, k1, b1) < 0.0f) << u;
        m11 |= (uint32_t)(fmaf(q1, k1, b1) < 0.0f) << u;
    }
    sb[0][pw2][g]     = (unsigned short)m00;
    sb[0][pw2 + 1][g] = (unsigned short)m01;
    sb[1][pw2][g]     = (unsigned short)m10;
    sb[1][pw2 + 1][g] = (unsigned short)m11;
    __syncthreads();

    {
        const int wp = t & 1;
        const int px = (t >> 1) & 63;
        const int br = t >> 7;
        const unsigned short* h = &sb[br][px][wp * 4];
        uint2 v;
        v.x = (uint32_t)h[0] | ((uint32_t)h[1] << 16);
        v.y = (uint32_t)h[2] | ((uint32_t)h[3] << 16);
        ((uint2*)abits)[((size_t)(br * BATCH + b) * IMGS + (ph + 1) * PADW + px + 1) * 2 + wp] = v;
    }
}

__device__ __forceinline__ int bcnt_acc(uint32_t xv, int acc) {
    int d;
    asm("v_bcnt_u32_b32 %0, %1, %2" : "=v"(d) : "v"(xv), "v"(acc));
    return d;
}
__device__ __forceinline__ int xacc4(uint4 a, uint4 w, int acc) {
    acc = bcnt_acc(a.x ^ w.x, acc);
    acc = bcnt_acc(a.y ^ w.y, acc);
    acc = bcnt_acc(a.z ^ w.z, acc);
    acc = bcnt_acc(a.w ^ w.w, acc);
    return acc;
}

__global__ __launch_bounds__(256, 8) void bconv_main(
    const uint32_t* __restrict__ abits_, const uint32_t* __restrict__ wrec_,
    const _Float16* __restrict__ pooledH, float* __restrict__ out)
{
    const int bid = blockIdx.x;        // ((branch*16 + b)*8 + ty)*8 + og
    const int og     = bid & 7;        // o-chunk of 16
    const int ty     = (bid >> 3) & 7;
    const int b      = (bid >> 6) & 15;
    const int branch = bid >> 10;
    const int t  = threadIdx.x;
    const int cp = t & 31;             // col pair -> cols 2cp, 2cp+1
    const int r  = t >> 5;             // 0..7
    const int gr = ty * 8 + r;         // output row

    // direct global loads of the 12 activation halo words (padded, zero guard)
    const uint4* ab = (const uint4*)abits_ + (size_t)(branch * BATCH + b) * IMGS
                    + (size_t)gr * PADW + 2 * cp;   // padded rows gr..gr+2, cols 2cp..2cp+3
    uint4 a[3][4];
    #pragma unroll
    for (int i = 0; i < 3; ++i)
        #pragma unroll
        for (int j = 0; j < 4; ++j)
            a[i][j] = ab[i * PADW + j];

    const bool fr0 = (gr == 0), fr2 = (gr == 63);
    const bool fc0 = (cp == 0), fc2 = (cp == 31);   // out0 left edge / out1 right edge

    const _Float16* prow = pooledH + (size_t)(b * CH) * (PH * PW) + gr * PW + 2 * cp;
    float* orow = out + (size_t)(b * 2 * CH + branch * CH) * (PH * PW) + gr * PW + 2 * cp;

    const int o_beg = og * 16;
    #pragma unroll 4
    for (int o = o_beg; o < o_beg + 16; ++o) {
        const uint4* rec = (const uint4*)(wrec_ + (size_t)(branch * 128 + o) * 48);
        int pc0 = 0, pc1 = 0;
        #pragma unroll
        for (int dy = 0; dy < 3; ++dy) {
            const uint4 w0 = rec[dy * 3 + 0];
            const uint4 w1 = rec[dy * 3 + 1];
            const uint4 w2 = rec[dy * 3 + 2];
            pc0 = xacc4(a[dy][0], w0, pc0);
            pc1 = xacc4(a[dy][1], w0, pc1);
            pc0 = xacc4(a[dy][1], w1, pc0);
            pc1 = xacc4(a[dy][2], w1, pc1);
            pc0 = xacc4(a[dy][2], w2, pc0);
            pc1 = xacc4(a[dy][3], w2, pc1);
        }
        // border correction: S = 1152 + corr - 2*pc (guard band a=0 -> tap adds popc(w))
        const int4  wcA = ((const int4*)rec)[9];    // cr0, cr2, cc0, cc2
        const int4  wcB = ((const int4*)rec)[10];   // k00, k02, k20, k22
        const fvec4 fsv = ((const fvec4*)rec)[11];  // sc, pb0, alpha, pb1
        const int baser = (fr0 ? wcA.x : 0) + (fr2 ? wcA.y : 0);
        const int cc0e  = wcA.z - (fr0 ? wcB.x : 0) - (fr2 ? wcB.z : 0);
        const int cc2e  = wcA.w - (fr0 ? wcB.y : 0) - (fr2 ? wcB.w : 0);
        const int S0 = 1152 + baser + (fc0 ? cc0e : 0) - 2 * pc0;
        const int S1 = 1152 + baser + (fc2 ? cc2e : 0) - 2 * pc1;

        float y0 = fsv.x * (float)S0 + fsv.y;
        float y1 = fsv.x * (float)S1 + fsv.y;
        y0 = fmaxf(y0, 0.f) + fsv.z * fminf(y0, 0.f) + fsv.w;
        y1 = fmaxf(y1, 0.f) + fsv.z * fminf(y1, 0.f) + fsv.w;
        const half2v pv = *(const half2v*)(prow + (size_t)o * (PH * PW));
        fvec2 st;
        st.x = (float)pv.x + y0;
        st.y = (float)pv.y + y1;
        __builtin_nontemporal_store(st, (fvec2*)(orow + (size_t)o * (PH * PW)));
    }
}

extern "C" void kernel_launch(void* const* d_in, const int* in_sizes, int n_in,
                              void* d_out, int out_size, void* d_ws, size_t ws_size,
                              hipStream_t stream)
{
    const float* x      = (const float*)d_in[0];
    const float* W1     = (const float*)d_in[1];
    const float* mvk1   = (const float*)d_in[2];
    const float* mvb1   = (const float*)d_in[3];
    const float* pb0_1  = (const float*)d_in[5];
    const float* alpha1 = (const float*)d_in[6];
    const float* pb1_1  = (const float*)d_in[7];
    const float* W2     = (const float*)d_in[8];
    const float* mvk2   = (const float*)d_in[9];
    const float* mvb2   = (const float*)d_in[10];
    const float* pb0_2  = (const float*)d_in[12];
    const float* alpha2 = (const float*)d_in[13];
    const float* pb1_2  = (const float*)d_in[14];
    float* out = (float*)d_out;

    char* ws = (char*)d_ws;
    _Float16* pooled = (_Float16*)ws;
    uint32_t* abits  = (uint32_t*)(ws + OFF_ABITS);
    uint32_t* wrec   = (uint32_t*)(ws + OFF_WREC);

    hipLaunchKernelGGL(prep_fused, dim3(1312), dim3(256), 0, stream,
                       x, mvk1, mvb1, mvk2, mvb2, W1, W2,
                       pb0_1, alpha1, pb1_1, pb0_2, alpha2, pb1_2,
                       pooled, abits, wrec);
    hipLaunchKernelGGL(bconv_main, dim3(2048), dim3(256), 0, stream,
                       abits, wrec, pooled, out);
}